// Round 6
// baseline (436.477 us; speedup 1.0000x reference)
//
#include <hip/hip_runtime.h>

#define CCH 384
#define HH 192
#define WWD 192
#define NIMG 2
#define HWP (HH * WWD)        // 36864 pixels per image
#define PTOT (NIMG * HWP)     // 73728
#define HEADS 12
#define HD 32
#define NWIN 24
#define WINS 576              // windows per image
#define EELEM ((size_t)NIMG * CCH * HWP)   // elems per tensor (28,311,552)
#define WMAT 147456           // 384*384

typedef __attribute__((ext_vector_type(8))) short bh8;            // 8 bf16 (MFMA frag)
typedef __attribute__((ext_vector_type(8))) unsigned short us8;
typedef __attribute__((ext_vector_type(4))) unsigned short us4;
typedef __attribute__((ext_vector_type(4))) float fx4;

__device__ __forceinline__ unsigned short f2bf(float f) {
    unsigned u = __float_as_uint(f);
    u += 0x7fffu + ((u >> 16) & 1u);      // round-to-nearest-even
    return (unsigned short)(u >> 16);
}

__device__ __forceinline__ void gload16(const void* g, void* l) {
    __builtin_amdgcn_global_load_lds(
        (const __attribute__((address_space(1))) void*)g,
        (__attribute__((address_space(3))) void*)l, 16, 0, 0);
}

// ---------------------------------------------------------------------------
// weights fp32 -> bf16 (qp_w, kp_w, vp_w, proj_w concatenated)
// ---------------------------------------------------------------------------
__global__ __launch_bounds__(256) void wcvt(
    const float* __restrict__ a, const float* __restrict__ b,
    const float* __restrict__ c, const float* __restrict__ d,
    unsigned short* __restrict__ o)
{
    int idx8 = (blockIdx.x * 256 + threadIdx.x) * 8;
    int which = idx8 / WMAT;
    int loc = idx8 - which * WMAT;
    const float* s = (which == 0) ? a : (which == 1) ? b : (which == 2) ? c : d;
    float4 v0 = *(const float4*)(s + loc);
    float4 v1 = *(const float4*)(s + loc + 4);
    us8 ov;
    ov[0] = f2bf(v0.x); ov[1] = f2bf(v0.y); ov[2] = f2bf(v0.z); ov[3] = f2bf(v0.w);
    ov[4] = f2bf(v1.x); ov[5] = f2bf(v1.y); ov[6] = f2bf(v1.z); ov[7] = f2bf(v1.w);
    *(us8*)(o + idx8) = ov;
}

// ---------------------------------------------------------------------------
// FUSED depthwise 3x3 + bias + window-gather transpose (v5).
// Block = ONE window (8x8) x 32 channels; grid = 1152 windows x 12 ch-chunks
//       = 13824 blocks (= 8 x 1728, XCD-chunked bijective swizzle).
// LDS halo: [32 ch][10 rows][12 cols] f32, channel stride 121 (odd ->
// conflict-free reads); 15.5 KB -> 8 blocks/CU (100% wave occupancy).
// Lane = channel (vector weight loads); thread = 1 channel x 8 pixels.
// ---------------------------------------------------------------------------
__global__ __launch_bounds__(256) void dwgather(
    const float* __restrict__ x,
    const float* __restrict__ qw, const float* __restrict__ qb,
    const float* __restrict__ kw, const float* __restrict__ kb,
    const float* __restrict__ vw, const float* __restrict__ vb,
    unsigned short* __restrict__ oq, unsigned short* __restrict__ ok,
    unsigned short* __restrict__ ov)
{
    __shared__ float halo[32 * 121];        // 15.5 KB

    // bijective XCD swizzle: 13824 = 8 * 1728
    int bid = blockIdx.x;
    int b = (bid & 7) * 1728 + (bid >> 3);
    // b = ((n*24 + wy)*12 + chv)*24 + wtx  (consecutive b: same strip, same XCD)
    int wtx   = b % 24;
    int rest  = b / 24;                     // 0..575
    int chv   = rest % 12;
    int nwy   = rest / 12;                  // 0..47
    int wy    = nwy % 24;
    int n     = nwy / 24;

    int h0 = wy * 8, w0 = wtx * 8;
    int tid = threadIdx.x;
    int c   = tid & 31;                     // channel within chunk
    int pxg = tid >> 5;                     // 0..7 = pixel row
    int cg  = chv * 32 + c;
    int widx = n * WINS + wy * NWIN + wtx;

    const float* xbase = x + (size_t)n * CCH * HWP + (size_t)(chv * 32) * HWP;

    // ---- stage halo: 32ch x 10 rows x 12 cols (cols w0-2 .. w0+9) ----
    for (int j = tid; j < 960; j += 256) {
        int seg = j % 3;
        int t   = j / 3;
        int rr  = t % 10;
        int cc  = t / 10;
        int hr  = h0 - 1 + rr;
        int cb  = w0 - 2 + seg * 4;
        float4 val = make_float4(0.f, 0.f, 0.f, 0.f);
        if (hr >= 0 && hr < HH) {
            const float* p = xbase + (size_t)cc * HWP + (size_t)hr * WWD;
            if (cb >= 0 && cb + 4 <= WWD) {
                val = *(const float4*)(p + cb);
            } else {
                if (cb + 0 >= 0 && cb + 0 < WWD) val.x = p[cb + 0];
                if (cb + 1 >= 0 && cb + 1 < WWD) val.y = p[cb + 1];
                if (cb + 2 >= 0 && cb + 2 < WWD) val.z = p[cb + 2];
                if (cb + 3 >= 0 && cb + 3 < WWD) val.w = p[cb + 3];
            }
        }
        int hb = cc * 121 + rr * 12 + seg * 4;
        halo[hb + 0] = val.x;
        halo[hb + 1] = val.y;
        halo[hb + 2] = val.z;
        halo[hb + 3] = val.w;
    }

    // ---- per-lane weights (vector loads, latency-hidden) ----
    float wq[9], wk[9], wv[9];
#pragma unroll
    for (int t = 0; t < 9; ++t) {
        wq[t] = qw[cg * 9 + t];
        wk[t] = kw[cg * 9 + t];
        wv[t] = vw[cg * 9 + t];
    }
    float bqv = qb[cg], bkv = kb[cg], bvv = vb[cg];

    __syncthreads();

    // ---- compute 8 pixels (row pxg), store 64B-contiguous per half-wave ----
#pragma unroll
    for (int i = 0; i < 8; ++i) {
        float sq = 0.f, sk = 0.f, sv = 0.f;
#pragma unroll
        for (int dr = 0; dr < 3; ++dr)
#pragma unroll
            for (int dc = 0; dc < 3; ++dc) {
                float xv = halo[c * 121 + (pxg + dr) * 12 + i + dc + 1];
                int t = dr * 3 + dc;
                sq = fmaf(xv, wq[t], sq);
                sk = fmaf(xv, wk[t], sk);
                sv = fmaf(xv, wv[t], sv);
            }
        size_t ob = ((size_t)widx * 64 + pxg * 8 + i) * CCH + cg;
        oq[ob] = f2bf(sq + bqv);
        ok[ob] = f2bf(sk + bkv);
        ov[ob] = f2bf(sv + bvv);
    }
}

// ---------------------------------------------------------------------------
// bf16 MFMA GEMM over channels (m97 structure: global_load_lds staging).
// Y: bf16 [p_wg][384]; W: bf16 [c_out][384] (both k-contiguous).
// 128x128 tile, BK=32, 4 waves, 4x4 16x16 frags/wave; linear [128][32] LDS.
// ORIENT 1: D[c][p] -> out bf16 [p][c], (acc+bias)*scale      (q, k)
// ORIENT 2: D[p][c] -> out bf16 [n][c][p_local], acc+bias     (v, transposed for attn)
// ORIENT 3: D[p][c] -> out fp32 standard [n][c][h][w], un-gather windows (proj)
// ---------------------------------------------------------------------------
template<int ORIENT>
__global__ __launch_bounds__(256) void pw_gemm(
    const unsigned short* __restrict__ Y, const unsigned short* __restrict__ Wb,
    const float* __restrict__ bias, float scale,
    unsigned short* __restrict__ outb, float* __restrict__ outf)
{
    __shared__ unsigned short Wt[128][32];   // linear, gload_lds dest
    __shared__ unsigned short Yt[128][32];

    int tid = threadIdx.x;
    int pp0 = blockIdx.x * 128;
    int cm0 = blockIdx.y * 128;
    int lid = tid & 63, wid = tid >> 6;
    int wr = wid >> 1, wc = wid & 1;
    int li = lid & 15, g = lid >> 4;

    // staging geometry: wave stages rows wid*32..wid*32+31; one issue = 16 rows
    int srow = (lid >> 2);               // 0..15 within 16-row group
    int scol = (lid & 3) * 8;            // 0,8,16,24 (u16)

    fx4 acc[4][4];
#pragma unroll
    for (int i = 0; i < 4; ++i)
#pragma unroll
        for (int j = 0; j < 4; ++j) acc[i][j] = (fx4){0.f, 0.f, 0.f, 0.f};

    typedef unsigned short (*tile_t)[32];
    tile_t Asrc = (ORIENT == 1) ? Wt : Yt;
    tile_t Bsrc = (ORIENT == 1) ? Yt : Wt;

    const unsigned short* Wg0 = Wb + (size_t)(cm0 + wid * 32 + srow) * CCH + scol;
    const unsigned short* Yg0 = Y  + (size_t)(pp0 + wid * 32 + srow) * CCH + scol;

    for (int kt = 0; kt < 12; ++kt) {
        int k0 = kt * 32;
        __syncthreads();                 // previous compute done
#pragma unroll
        for (int qi = 0; qi < 2; ++qi) {
            gload16(Wg0 + (size_t)qi * 16 * CCH + k0, &Wt[wid * 32 + qi * 16][0]);
            gload16(Yg0 + (size_t)qi * 16 * CCH + k0, &Yt[wid * 32 + qi * 16][0]);
        }
        __syncthreads();                 // vmcnt(0) drain -> tiles visible

        bh8 a[4], b[4];
#pragma unroll
        for (int mf = 0; mf < 4; ++mf)
            a[mf] = *(const bh8*)&Asrc[wr * 64 + mf * 16 + li][g * 8];
#pragma unroll
        for (int nf = 0; nf < 4; ++nf)
            b[nf] = *(const bh8*)&Bsrc[wc * 64 + nf * 16 + li][g * 8];
#pragma unroll
        for (int mf = 0; mf < 4; ++mf)
#pragma unroll
            for (int nf = 0; nf < 4; ++nf)
                acc[mf][nf] = __builtin_amdgcn_mfma_f32_16x16x32_bf16(
                    a[mf], b[nf], acc[mf][nf], 0, 0, 0);
    }

    if (ORIENT == 1) {
#pragma unroll
        for (int mf = 0; mf < 4; ++mf) {
            int c = cm0 + wr * 64 + mf * 16 + g * 4;
            float4 bv = *(const float4*)&bias[c];
#pragma unroll
            for (int nf = 0; nf < 4; ++nf) {
                int p = pp0 + wc * 64 + nf * 16 + li;
                us4 o;
                o[0] = f2bf((acc[mf][nf][0] + bv.x) * scale);
                o[1] = f2bf((acc[mf][nf][1] + bv.y) * scale);
                o[2] = f2bf((acc[mf][nf][2] + bv.z) * scale);
                o[3] = f2bf((acc[mf][nf][3] + bv.w) * scale);
                *(us4*)(outb + (size_t)p * CCH + c) = o;
            }
        }
    } else if (ORIENT == 2) {
#pragma unroll
        for (int nf = 0; nf < 4; ++nf) {
            int c = cm0 + wc * 64 + nf * 16 + li;
            float bv = bias[c];
#pragma unroll
            for (int mf = 0; mf < 4; ++mf) {
                int p = pp0 + wr * 64 + mf * 16 + g * 4;
                int n = p / HWP;
                int pl = p - n * HWP;
                us4 o;
                o[0] = f2bf(acc[mf][nf][0] + bv);
                o[1] = f2bf(acc[mf][nf][1] + bv);
                o[2] = f2bf(acc[mf][nf][2] + bv);
                o[3] = f2bf(acc[mf][nf][3] + bv);
                *(us4*)(outb + (size_t)(n * CCH + c) * HWP + pl) = o;
            }
        }
    } else {   // ORIENT 3: fp32 std layout, inverse window gather
#pragma unroll
        for (int nf = 0; nf < 4; ++nf) {
            int c = cm0 + wc * 64 + nf * 16 + li;
            float bv = bias[c];
#pragma unroll
            for (int mf = 0; mf < 4; ++mf) {
                int p = pp0 + wr * 64 + mf * 16 + g * 4;
                int n = p / HWP;
                int rem = p - n * HWP;
                int win = rem >> 6, t = rem & 63;
                int h = (win / NWIN) * 8 + (t >> 3);
                int w = (win % NWIN) * 8 + (t & 7);
                float4 o;
                o.x = acc[mf][nf][0] + bv;
                o.y = acc[mf][nf][1] + bv;
                o.z = acc[mf][nf][2] + bv;
                o.w = acc[mf][nf][3] + bv;
                *(float4*)(outf + (size_t)(n * CCH + c) * HWP + h * WWD + w) = o;
            }
        }
    }
}

// ---------------------------------------------------------------------------
// MFMA window attention. block = one window (64 tokens); 4 waves x 3 heads.
// q,k: bf16 [p_wg][384]; v: bf16 [n][c][p_local] (= V^T); out: bf16 [p_wg][384].
// ---------------------------------------------------------------------------
__global__ __launch_bounds__(256) void attn(
    const unsigned short* __restrict__ q, const unsigned short* __restrict__ k,
    const unsigned short* __restrict__ v, const float* __restrict__ rpb,
    unsigned short* __restrict__ o)
{
    __shared__ float rpbs[225 * HEADS];
    __shared__ unsigned short Pl[4][64][72];

    int tid = threadIdx.x, lid = tid & 63, wid = tid >> 6;
    int wl = blockIdx.x;
    int n = wl / WINS, winl = wl - n * WINS;
    int li = lid & 15, g = lid >> 4;

    for (int i = tid; i < 225 * HEADS; i += 256) rpbs[i] = rpb[i];
    __syncthreads();

    const fx4 z = (fx4){0.f, 0.f, 0.f, 0.f};

    for (int hq = wid; hq < HEADS; hq += 4) {
        const unsigned short* qp = q + (size_t)(wl * 64) * CCH + hq * HD + g * 8;
        const unsigned short* kp = k + (size_t)(wl * 64) * CCH + hq * HD + g * 8;
        bh8 aq[4], bk[4];
#pragma unroll
        for (int mf = 0; mf < 4; ++mf)
            aq[mf] = *(const bh8*)(qp + (size_t)(mf * 16 + li) * CCH);
#pragma unroll
        for (int nf = 0; nf < 4; ++nf)
            bk[nf] = *(const bh8*)(kp + (size_t)(nf * 16 + li) * CCH);

        fx4 s[4][4];
#pragma unroll
        for (int mf = 0; mf < 4; ++mf)
#pragma unroll
            for (int nf = 0; nf < 4; ++nf)
                s[mf][nf] = __builtin_amdgcn_mfma_f32_16x16x32_bf16(aq[mf], bk[nf], z, 0, 0, 0);

        // relative position bias (analytic index)
#pragma unroll
        for (int mf = 0; mf < 4; ++mf)
#pragma unroll
            for (int nf = 0; nf < 4; ++nf)
#pragma unroll
                for (int r = 0; r < 4; ++r) {
                    int tq = mf * 16 + g * 4 + r, tk = nf * 16 + li;
                    int dy = (tq >> 3) - (tk >> 3) + 7;
                    int dx = (tq & 7) - (tk & 7) + 7;
                    s[mf][nf][r] += rpbs[(dy * 15 + dx) * HEADS + hq];
                }

        // softmax across tk (lane group of 16 shares a row set)
        float inv_[4][4];
#pragma unroll
        for (int mf = 0; mf < 4; ++mf)
#pragma unroll
            for (int r = 0; r < 4; ++r) {
                float m = s[mf][0][r];
#pragma unroll
                for (int nf = 1; nf < 4; ++nf) m = fmaxf(m, s[mf][nf][r]);
                m = fmaxf(m, __shfl_xor(m, 1));
                m = fmaxf(m, __shfl_xor(m, 2));
                m = fmaxf(m, __shfl_xor(m, 4));
                m = fmaxf(m, __shfl_xor(m, 8));
                float sum = 0.f;
#pragma unroll
                for (int nf = 0; nf < 4; ++nf) {
                    float e = __expf(s[mf][nf][r] - m);
                    s[mf][nf][r] = e;
                    sum += e;
                }
                sum += __shfl_xor(sum, 1);
                sum += __shfl_xor(sum, 2);
                sum += __shfl_xor(sum, 4);
                sum += __shfl_xor(sum, 8);
                inv_[mf][r] = 1.f / sum;
            }

        // P -> per-wave LDS, bf16, row-major [tq][tk]
#pragma unroll
        for (int mf = 0; mf < 4; ++mf)
#pragma unroll
            for (int nf = 0; nf < 4; ++nf)
#pragma unroll
                for (int r = 0; r < 4; ++r)
                    Pl[wid][mf * 16 + g * 4 + r][nf * 16 + li] =
                        f2bf(s[mf][nf][r] * inv_[mf][r]);

        // O^T = V^T x P^T : D[d][tq]
        fx4 o2[2][4];
#pragma unroll
        for (int m2 = 0; m2 < 2; ++m2)
#pragma unroll
            for (int nf = 0; nf < 4; ++nf) o2[m2][nf] = z;
#pragma unroll
        for (int ks = 0; ks < 2; ++ks) {
            bh8 av[2], bp[4];
#pragma unroll
            for (int m2 = 0; m2 < 2; ++m2)
                av[m2] = *(const bh8*)(v + (size_t)(n * CCH + hq * HD + m2 * 16 + li) * HWP
                                         + winl * 64 + ks * 32 + g * 8);
#pragma unroll
            for (int nf = 0; nf < 4; ++nf)
                bp[nf] = *(const bh8*)&Pl[wid][nf * 16 + li][ks * 32 + g * 8];
#pragma unroll
            for (int m2 = 0; m2 < 2; ++m2)
#pragma unroll
                for (int nf = 0; nf < 4; ++nf)
                    o2[m2][nf] = __builtin_amdgcn_mfma_f32_16x16x32_bf16(
                        av[m2], bp[nf], o2[m2][nf], 0, 0, 0);
        }
#pragma unroll
        for (int nf = 0; nf < 4; ++nf) {
            int tq = nf * 16 + li;
#pragma unroll
            for (int m2 = 0; m2 < 2; ++m2) {
                int d = hq * HD + m2 * 16 + g * 4;
                us4 ov;
                ov[0] = f2bf(o2[m2][nf][0]);
                ov[1] = f2bf(o2[m2][nf][1]);
                ov[2] = f2bf(o2[m2][nf][2]);
                ov[3] = f2bf(o2[m2][nf][3]);
                *(us4*)(o + (size_t)(wl * 64 + tq) * CCH + d) = ov;
            }
        }
    }
}

// ---------------------------------------------------------------------------
extern "C" void kernel_launch(void* const* d_in, const int* in_sizes, int n_in,
                              void* d_out, int out_size, void* d_ws, size_t ws_size,
                              hipStream_t stream) {
    const float* vid  = (const float*)d_in[0];
    const float* qd_w = (const float*)d_in[1];
    const float* qd_b = (const float*)d_in[2];
    const float* qp_w = (const float*)d_in[3];
    const float* qp_b = (const float*)d_in[4];
    const float* kd_w = (const float*)d_in[5];
    const float* kd_b = (const float*)d_in[6];
    const float* kp_w = (const float*)d_in[7];
    const float* kp_b = (const float*)d_in[8];
    const float* vd_w = (const float*)d_in[9];
    const float* vd_b = (const float*)d_in[10];
    const float* vp_w = (const float*)d_in[11];
    const float* vp_b = (const float*)d_in[12];
    const float* rpb  = (const float*)d_in[13];
    const float* pj_w = (const float*)d_in[14];
    const float* pj_b = (const float*)d_in[15];

    unsigned short* ws16 = (unsigned short*)d_ws;
    unsigned short* tr0 = ws16 + 3 * EELEM;     // [p_wg][c] bf16 (q,k,v pre-GEMM)
    unsigned short* tr1 = ws16 + 4 * EELEM;
    unsigned short* tr2 = ws16 + 5 * EELEM;
    unsigned short* Wb  = ws16 + 6 * EELEM;     // 4 x 147456 bf16
    unsigned short* qb  = ws16;                 // post-GEMM q,k,v
    unsigned short* kb  = ws16 + EELEM;
    unsigned short* vb  = ws16 + 2 * EELEM;
    unsigned short* ob  = tr0;                  // attn out reuses tr region

    wcvt<<<288, 256, 0, stream>>>(qp_w, kp_w, vp_w, pj_w, Wb);
    dwgather<<<NIMG * WINS * 12, 256, 0, stream>>>(
        vid, qd_w, qd_b, kd_w, kd_b, vd_w, vd_b, tr0, tr1, tr2);

    dim3 gg(PTOT / 128, 3);
    const float scale = 0.17677669529663687f;   // 32^-0.5 folded into q
    pw_gemm<1><<<gg, 256, 0, stream>>>(tr0, Wb,             qp_b, scale, qb, nullptr);
    pw_gemm<1><<<gg, 256, 0, stream>>>(tr1, Wb + WMAT,      kp_b, 1.0f,  kb, nullptr);
    pw_gemm<2><<<gg, 256, 0, stream>>>(tr2, Wb + 2 * WMAT,  vp_b, 1.0f,  vb, nullptr);

    attn<<<NIMG * WINS, 256, 0, stream>>>(qb, kb, vb, rpb, ob);

    pw_gemm<3><<<gg, 256, 0, stream>>>(ob, Wb + 3 * WMAT, pj_b, 1.0f, nullptr, (float*)d_out);
}

// Round 7
// 413.391 us; speedup vs baseline: 1.0558x; 1.0558x over previous
//
#include <hip/hip_runtime.h>

#define CCH 384
#define HH 192
#define WWD 192
#define NIMG 2
#define HWP (HH * WWD)        // 36864 pixels per image
#define PTOT (NIMG * HWP)     // 73728
#define HEADS 12
#define HD 32
#define NWIN 24
#define WINS 576              // windows per image
#define EELEM ((size_t)NIMG * CCH * HWP)   // elems per tensor (28,311,552)
#define WMAT 147456           // 384*384

typedef __attribute__((ext_vector_type(8))) short bh8;            // 8 bf16 (MFMA frag)
typedef __attribute__((ext_vector_type(8))) unsigned short us8;
typedef __attribute__((ext_vector_type(4))) unsigned short us4;
typedef __attribute__((ext_vector_type(4))) float fx4;

__device__ __forceinline__ unsigned short f2bf(float f) {
    unsigned u = __float_as_uint(f);
    u += 0x7fffu + ((u >> 16) & 1u);      // round-to-nearest-even
    return (unsigned short)(u >> 16);
}

__device__ __forceinline__ void gload16(const void* g, void* l) {
    __builtin_amdgcn_global_load_lds(
        (const __attribute__((address_space(1))) void*)g,
        (__attribute__((address_space(3))) void*)l, 16, 0, 0);
}

// ---------------------------------------------------------------------------
// weights fp32 -> bf16 (qp_w, kp_w, vp_w, proj_w concatenated)
// ---------------------------------------------------------------------------
__global__ __launch_bounds__(256) void wcvt(
    const float* __restrict__ a, const float* __restrict__ b,
    const float* __restrict__ c, const float* __restrict__ d,
    unsigned short* __restrict__ o)
{
    int idx8 = (blockIdx.x * 256 + threadIdx.x) * 8;
    int which = idx8 / WMAT;
    int loc = idx8 - which * WMAT;
    const float* s = (which == 0) ? a : (which == 1) ? b : (which == 2) ? c : d;
    float4 v0 = *(const float4*)(s + loc);
    float4 v1 = *(const float4*)(s + loc + 4);
    us8 ov;
    ov[0] = f2bf(v0.x); ov[1] = f2bf(v0.y); ov[2] = f2bf(v0.z); ov[3] = f2bf(v0.w);
    ov[4] = f2bf(v1.x); ov[5] = f2bf(v1.y); ov[6] = f2bf(v1.z); ov[7] = f2bf(v1.w);
    *(us8*)(o + idx8) = ov;
}

// ---------------------------------------------------------------------------
// depthwise weight transpose: [384][9] -> [9][384] fp32, for q,k,v.
// (lane-per-channel loads in dwgather become coalesced)
// ---------------------------------------------------------------------------
__global__ __launch_bounds__(256) void wprep(
    const float* __restrict__ q, const float* __restrict__ k,
    const float* __restrict__ v, float* __restrict__ o)
{
    int idx = blockIdx.x * 256 + threadIdx.x;
    if (idx >= 3 * 9 * CCH) return;
    int ten = idx / (9 * CCH);
    int rem = idx - ten * (9 * CCH);
    int tap = rem / CCH;
    int c   = rem - tap * CCH;
    const float* s = (ten == 0) ? q : (ten == 1) ? k : v;
    o[idx] = s[c * 9 + tap];
}

// ---------------------------------------------------------------------------
// FUSED depthwise 3x3 + bias + window-gather transpose (v6 = v3 geometry +
// transposed weights). Block = ONE window (8x8) x 64 channels;
// grid = 1152 windows x 6 ch-chunks = 6912 blocks (8 x 864 XCD swizzle).
// LDS halo: [64 ch][10 rows][12 cols] f32, stride 121 (odd -> conflict-free).
// Lane = channel; weights read from [tap][384] layout (coalesced).
// ---------------------------------------------------------------------------
__global__ __launch_bounds__(256) void dwgather(
    const float* __restrict__ x,
    const float* __restrict__ wt,       // [3][9][384] fp32 transposed dw weights
    const float* __restrict__ qb, const float* __restrict__ kb,
    const float* __restrict__ vb,
    unsigned short* __restrict__ oq, unsigned short* __restrict__ ok,
    unsigned short* __restrict__ ov)
{
    __shared__ float halo[64 * 121];        // 30.25 KB

    // bijective XCD swizzle: 6912 = 8 * 864
    int bid = blockIdx.x;
    int b = (bid & 7) * 864 + (bid >> 3);
    int wtx  = b % 24;
    int strip = b / 24;                     // 0..287
    int chv  = strip % 6;
    int nwy  = strip / 6;                   // 0..47
    int wy   = nwy % 24;
    int n    = nwy / 24;

    int h0 = wy * 8, w0 = wtx * 8;
    int tid = threadIdx.x;
    int c   = tid & 63;                     // channel within chunk (lane-varying)
    int pxg = tid >> 6;                     // wave id: owns pixels pxg*16..+15
    int cg  = chv * 64 + c;
    int widx = n * WINS + wy * NWIN + wtx;

    const float* xbase = x + (size_t)n * CCH * HWP + (size_t)(chv * 64) * HWP;

    // ---- stage halo: 64ch x 10 rows x 12 cols (cols w0-2 .. w0+9) ----
    for (int j = tid; j < 1920; j += 256) {
        int seg = j % 3;
        int t   = j / 3;
        int rr  = t % 10;
        int cc  = t / 10;
        int hr  = h0 - 1 + rr;
        int cb  = w0 - 2 + seg * 4;
        float4 val = make_float4(0.f, 0.f, 0.f, 0.f);
        if (hr >= 0 && hr < HH) {
            const float* p = xbase + (size_t)cc * HWP + (size_t)hr * WWD;
            if (cb >= 0 && cb + 4 <= WWD) {
                val = *(const float4*)(p + cb);
            } else {
                if (cb + 0 >= 0 && cb + 0 < WWD) val.x = p[cb + 0];
                if (cb + 1 >= 0 && cb + 1 < WWD) val.y = p[cb + 1];
                if (cb + 2 >= 0 && cb + 2 < WWD) val.z = p[cb + 2];
                if (cb + 3 >= 0 && cb + 3 < WWD) val.w = p[cb + 3];
            }
        }
        int hb = cc * 121 + rr * 12 + seg * 4;
        halo[hb + 0] = val.x;
        halo[hb + 1] = val.y;
        halo[hb + 2] = val.z;
        halo[hb + 3] = val.w;
    }

    // ---- per-lane weights, COALESCED ([tap][384] layout) ----
    float wq[9], wk[9], wv[9];
#pragma unroll
    for (int t = 0; t < 9; ++t) {
        wq[t] = wt[t * CCH + cg];
        wk[t] = wt[9 * CCH + t * CCH + cg];
        wv[t] = wt[18 * CCH + t * CCH + cg];
    }
    float bqv = qb[cg], bkv = kb[cg], bvv = vb[cg];

    __syncthreads();

    // ---- compute 16 pixels, store 128B-contiguous (64 lanes = 64 channels) --
#pragma unroll
    for (int i = 0; i < 16; ++i) {
        int px = pxg * 16 + i;
        int pr = px >> 3, pc = px & 7;
        float sq = 0.f, sk = 0.f, sv = 0.f;
#pragma unroll
        for (int dr = 0; dr < 3; ++dr)
#pragma unroll
            for (int dc = 0; dc < 3; ++dc) {
                float xv = halo[c * 121 + (pr + dr) * 12 + pc + dc + 1];
                int t = dr * 3 + dc;
                sq = fmaf(xv, wq[t], sq);
                sk = fmaf(xv, wk[t], sk);
                sv = fmaf(xv, wv[t], sv);
            }
        size_t ob = ((size_t)widx * 64 + px) * CCH + cg;
        oq[ob] = f2bf(sq + bqv);
        ok[ob] = f2bf(sk + bkv);
        ov[ob] = f2bf(sv + bvv);
    }
}

// ---------------------------------------------------------------------------
// bf16 MFMA GEMM (m97 structure: double-buffered global_load_lds, 1 barrier
// per K-step, next-tile loads in flight during MFMA).
// Y: bf16 [p_wg][384]; W: bf16 [c_out][384]. 128x128 tile, BK=32, 4 waves.
// ORIENT 1: D[c][p] -> out bf16 [p][c], (acc+bias)*scale      (q, k)
// ORIENT 2: D[p][c] -> out bf16 [n][c][p_local], acc+bias     (v, transposed)
// ORIENT 3: D[p][c] -> out fp32 std [n][c][h][w], un-gather   (proj)
// ---------------------------------------------------------------------------
template<int ORIENT>
__global__ __launch_bounds__(256) void pw_gemm(
    const unsigned short* __restrict__ Y, const unsigned short* __restrict__ Wb,
    const float* __restrict__ bias, float scale,
    unsigned short* __restrict__ outb, float* __restrict__ outf)
{
    __shared__ unsigned short Wt[2][128][32];   // linear, gload_lds dest
    __shared__ unsigned short Yt[2][128][32];

    int tid = threadIdx.x;
    int pp0 = blockIdx.x * 128;
    int cm0 = blockIdx.y * 128;
    int lid = tid & 63, wid = tid >> 6;
    int wr = wid >> 1, wc = wid & 1;
    int li = lid & 15, g = lid >> 4;

    // staging geometry: wave stages rows wid*32..+31; one issue = 16 rows
    int srow = (lid >> 2);               // 0..15 within 16-row group
    int scol = (lid & 3) * 8;            // 0,8,16,24 (u16)

    fx4 acc[4][4];
#pragma unroll
    for (int i = 0; i < 4; ++i)
#pragma unroll
        for (int j = 0; j < 4; ++j) acc[i][j] = (fx4){0.f, 0.f, 0.f, 0.f};

    typedef unsigned short (*tile3)[128][32];
    tile3 A3 = (ORIENT == 1) ? Wt : Yt;
    tile3 B3 = (ORIENT == 1) ? Yt : Wt;

    const unsigned short* Wg0 = Wb + (size_t)(cm0 + wid * 32 + srow) * CCH + scol;
    const unsigned short* Yg0 = Y  + (size_t)(pp0 + wid * 32 + srow) * CCH + scol;

    // prologue: stage tile 0 into buffer 0
#pragma unroll
    for (int qi = 0; qi < 2; ++qi) {
        gload16(Wg0 + (size_t)qi * 16 * CCH, &Wt[0][wid * 32 + qi * 16][0]);
        gload16(Yg0 + (size_t)qi * 16 * CCH, &Yt[0][wid * 32 + qi * 16][0]);
    }
    __syncthreads();                     // vmcnt(0) drain + barrier

    for (int kt = 0; kt < 12; ++kt) {
        int cur = kt & 1;
        if (kt < 11) {                   // issue NEXT tile (overlaps MFMA below)
            int k1 = (kt + 1) * 32;
#pragma unroll
            for (int qi = 0; qi < 2; ++qi) {
                gload16(Wg0 + (size_t)qi * 16 * CCH + k1, &Wt[cur ^ 1][wid * 32 + qi * 16][0]);
                gload16(Yg0 + (size_t)qi * 16 * CCH + k1, &Yt[cur ^ 1][wid * 32 + qi * 16][0]);
            }
        }

        bh8 a[4], b[4];
#pragma unroll
        for (int mf = 0; mf < 4; ++mf)
            a[mf] = *(const bh8*)&A3[cur][wr * 64 + mf * 16 + li][g * 8];
#pragma unroll
        for (int nf = 0; nf < 4; ++nf)
            b[nf] = *(const bh8*)&B3[cur][wc * 64 + nf * 16 + li][g * 8];
#pragma unroll
        for (int mf = 0; mf < 4; ++mf)
#pragma unroll
            for (int nf = 0; nf < 4; ++nf)
                acc[mf][nf] = __builtin_amdgcn_mfma_f32_16x16x32_bf16(
                    a[mf], b[nf], acc[mf][nf], 0, 0, 0);

        __syncthreads();                 // drains vmcnt(0): next tile ready,
    }                                    // and all reads of cur done

    if (ORIENT == 1) {
#pragma unroll
        for (int mf = 0; mf < 4; ++mf) {
            int c = cm0 + wr * 64 + mf * 16 + g * 4;
            float4 bv = *(const float4*)&bias[c];
#pragma unroll
            for (int nf = 0; nf < 4; ++nf) {
                int p = pp0 + wc * 64 + nf * 16 + li;
                us4 o;
                o[0] = f2bf((acc[mf][nf][0] + bv.x) * scale);
                o[1] = f2bf((acc[mf][nf][1] + bv.y) * scale);
                o[2] = f2bf((acc[mf][nf][2] + bv.z) * scale);
                o[3] = f2bf((acc[mf][nf][3] + bv.w) * scale);
                *(us4*)(outb + (size_t)p * CCH + c) = o;
            }
        }
    } else if (ORIENT == 2) {
#pragma unroll
        for (int nf = 0; nf < 4; ++nf) {
            int c = cm0 + wc * 64 + nf * 16 + li;
            float bv = bias[c];
#pragma unroll
            for (int mf = 0; mf < 4; ++mf) {
                int p = pp0 + wr * 64 + mf * 16 + g * 4;
                int n = p / HWP;
                int pl = p - n * HWP;
                us4 o;
                o[0] = f2bf(acc[mf][nf][0] + bv);
                o[1] = f2bf(acc[mf][nf][1] + bv);
                o[2] = f2bf(acc[mf][nf][2] + bv);
                o[3] = f2bf(acc[mf][nf][3] + bv);
                *(us4*)(outb + (size_t)(n * CCH + c) * HWP + pl) = o;
            }
        }
    } else {   // ORIENT 3: fp32 std layout, inverse window gather
#pragma unroll
        for (int nf = 0; nf < 4; ++nf) {
            int c = cm0 + wc * 64 + nf * 16 + li;
            float bv = bias[c];
#pragma unroll
            for (int mf = 0; mf < 4; ++mf) {
                int p = pp0 + wr * 64 + mf * 16 + g * 4;
                int n = p / HWP;
                int rem = p - n * HWP;
                int win = rem >> 6, t = rem & 63;
                int h = (win / NWIN) * 8 + (t >> 3);
                int w = (win % NWIN) * 8 + (t & 7);
                float4 o;
                o.x = acc[mf][nf][0] + bv;
                o.y = acc[mf][nf][1] + bv;
                o.z = acc[mf][nf][2] + bv;
                o.w = acc[mf][nf][3] + bv;
                *(float4*)(outf + (size_t)(n * CCH + c) * HWP + h * WWD + w) = o;
            }
        }
    }
}

// ---------------------------------------------------------------------------
// MFMA window attention. block = one window (64 tokens); 4 waves x 3 heads.
// q,k: bf16 [p_wg][384]; v: bf16 [n][c][p_local] (= V^T); out: bf16 [p_wg][384].
// ---------------------------------------------------------------------------
__global__ __launch_bounds__(256) void attn(
    const unsigned short* __restrict__ q, const unsigned short* __restrict__ k,
    const unsigned short* __restrict__ v, const float* __restrict__ rpb,
    unsigned short* __restrict__ o)
{
    __shared__ float rpbs[225 * HEADS];
    __shared__ unsigned short Pl[4][64][72];

    int tid = threadIdx.x, lid = tid & 63, wid = tid >> 6;
    int wl = blockIdx.x;
    int n = wl / WINS, winl = wl - n * WINS;
    int li = lid & 15, g = lid >> 4;

    for (int i = tid; i < 225 * HEADS; i += 256) rpbs[i] = rpb[i];
    __syncthreads();

    const fx4 z = (fx4){0.f, 0.f, 0.f, 0.f};

    for (int hq = wid; hq < HEADS; hq += 4) {
        const unsigned short* qp = q + (size_t)(wl * 64) * CCH + hq * HD + g * 8;
        const unsigned short* kp = k + (size_t)(wl * 64) * CCH + hq * HD + g * 8;
        bh8 aq[4], bk[4];
#pragma unroll
        for (int mf = 0; mf < 4; ++mf)
            aq[mf] = *(const bh8*)(qp + (size_t)(mf * 16 + li) * CCH);
#pragma unroll
        for (int nf = 0; nf < 4; ++nf)
            bk[nf] = *(const bh8*)(kp + (size_t)(nf * 16 + li) * CCH);

        fx4 s[4][4];
#pragma unroll
        for (int mf = 0; mf < 4; ++mf)
#pragma unroll
            for (int nf = 0; nf < 4; ++nf)
                s[mf][nf] = __builtin_amdgcn_mfma_f32_16x16x32_bf16(aq[mf], bk[nf], z, 0, 0, 0);

        // relative position bias (analytic index)
#pragma unroll
        for (int mf = 0; mf < 4; ++mf)
#pragma unroll
            for (int nf = 0; nf < 4; ++nf)
#pragma unroll
                for (int r = 0; r < 4; ++r) {
                    int tq = mf * 16 + g * 4 + r, tk = nf * 16 + li;
                    int dy = (tq >> 3) - (tk >> 3) + 7;
                    int dx = (tq & 7) - (tk & 7) + 7;
                    s[mf][nf][r] += rpbs[(dy * 15 + dx) * HEADS + hq];
                }

        // softmax across tk (lane group of 16 shares a row set)
        float inv_[4][4];
#pragma unroll
        for (int mf = 0; mf < 4; ++mf)
#pragma unroll
            for (int r = 0; r < 4; ++r) {
                float m = s[mf][0][r];
#pragma unroll
                for (int nf = 1; nf < 4; ++nf) m = fmaxf(m, s[mf][nf][r]);
                m = fmaxf(m, __shfl_xor(m, 1));
                m = fmaxf(m, __shfl_xor(m, 2));
                m = fmaxf(m, __shfl_xor(m, 4));
                m = fmaxf(m, __shfl_xor(m, 8));
                float sum = 0.f;
#pragma unroll
                for (int nf = 0; nf < 4; ++nf) {
                    float e = __expf(s[mf][nf][r] - m);
                    s[mf][nf][r] = e;
                    sum += e;
                }
                sum += __shfl_xor(sum, 1);
                sum += __shfl_xor(sum, 2);
                sum += __shfl_xor(sum, 4);
                sum += __shfl_xor(sum, 8);
                inv_[mf][r] = 1.f / sum;
            }

        // P -> per-wave LDS, bf16, row-major [tq][tk]
#pragma unroll
        for (int mf = 0; mf < 4; ++mf)
#pragma unroll
            for (int nf = 0; nf < 4; ++nf)
#pragma unroll
                for (int r = 0; r < 4; ++r)
                    Pl[wid][mf * 16 + g * 4 + r][nf * 16 + li] =
                        f2bf(s[mf][nf][r] * inv_[mf][r]);

        // O^T = V^T x P^T : D[d][tq]
        fx4 o2[2][4];
#pragma unroll
        for (int m2 = 0; m2 < 2; ++m2)
#pragma unroll
            for (int nf = 0; nf < 4; ++nf) o2[m2][nf] = z;
#pragma unroll
        for (int ks = 0; ks < 2; ++ks) {
            bh8 av[2], bp[4];
#pragma unroll
            for (int m2 = 0; m2 < 2; ++m2)
                av[m2] = *(const bh8*)(v + (size_t)(n * CCH + hq * HD + m2 * 16 + li) * HWP
                                         + winl * 64 + ks * 32 + g * 8);
#pragma unroll
            for (int nf = 0; nf < 4; ++nf)
                bp[nf] = *(const bh8*)&Pl[wid][nf * 16 + li][ks * 32 + g * 8];
#pragma unroll
            for (int m2 = 0; m2 < 2; ++m2)
#pragma unroll
                for (int nf = 0; nf < 4; ++nf)
                    o2[m2][nf] = __builtin_amdgcn_mfma_f32_16x16x32_bf16(
                        av[m2], bp[nf], o2[m2][nf], 0, 0, 0);
        }
#pragma unroll
        for (int nf = 0; nf < 4; ++nf) {
            int tq = nf * 16 + li;
#pragma unroll
            for (int m2 = 0; m2 < 2; ++m2) {
                int d = hq * HD + m2 * 16 + g * 4;
                us4 ov;
                ov[0] = f2bf(o2[m2][nf][0]);
                ov[1] = f2bf(o2[m2][nf][1]);
                ov[2] = f2bf(o2[m2][nf][2]);
                ov[3] = f2bf(o2[m2][nf][3]);
                *(us4*)(o + (size_t)(wl * 64 + tq) * CCH + d) = ov;
            }
        }
    }
}

// ---------------------------------------------------------------------------
extern "C" void kernel_launch(void* const* d_in, const int* in_sizes, int n_in,
                              void* d_out, int out_size, void* d_ws, size_t ws_size,
                              hipStream_t stream) {
    const float* vid  = (const float*)d_in[0];
    const float* qd_w = (const float*)d_in[1];
    const float* qd_b = (const float*)d_in[2];
    const float* qp_w = (const float*)d_in[3];
    const float* qp_b = (const float*)d_in[4];
    const float* kd_w = (const float*)d_in[5];
    const float* kd_b = (const float*)d_in[6];
    const float* kp_w = (const float*)d_in[7];
    const float* kp_b = (const float*)d_in[8];
    const float* vd_w = (const float*)d_in[9];
    const float* vd_b = (const float*)d_in[10];
    const float* vp_w = (const float*)d_in[11];
    const float* vp_b = (const float*)d_in[12];
    const float* rpb  = (const float*)d_in[13];
    const float* pj_w = (const float*)d_in[14];
    const float* pj_b = (const float*)d_in[15];

    unsigned short* ws16 = (unsigned short*)d_ws;
    unsigned short* tr0 = ws16 + 3 * EELEM;     // [p_wg][c] bf16 (q,k,v pre-GEMM)
    unsigned short* tr1 = ws16 + 4 * EELEM;
    unsigned short* tr2 = ws16 + 5 * EELEM;
    unsigned short* Wb  = ws16 + 6 * EELEM;     // 4 x 147456 bf16
    float* dwT          = (float*)(Wb + 4 * WMAT);  // [3][9][384] fp32
    unsigned short* qb  = ws16;                 // post-GEMM q,k,v
    unsigned short* kb  = ws16 + EELEM;
    unsigned short* vb  = ws16 + 2 * EELEM;
    unsigned short* ob  = tr0;                  // attn out reuses tr region

    wcvt<<<288, 256, 0, stream>>>(qp_w, kp_w, vp_w, pj_w, Wb);
    wprep<<<41, 256, 0, stream>>>(qd_w, kd_w, vd_w, dwT);
    dwgather<<<NIMG * WINS * 6, 256, 0, stream>>>(
        vid, dwT, qd_b, kd_b, vd_b, tr0, tr1, tr2);

    dim3 gg(PTOT / 128, 3);
    const float scale = 0.17677669529663687f;   // 32^-0.5 folded into q
    pw_gemm<1><<<gg, 256, 0, stream>>>(tr0, Wb,             qp_b, scale, qb, nullptr);
    pw_gemm<1><<<gg, 256, 0, stream>>>(tr1, Wb + WMAT,      kp_b, 1.0f,  kb, nullptr);
    pw_gemm<2><<<gg, 256, 0, stream>>>(tr2, Wb + 2 * WMAT,  vp_b, 1.0f,  vb, nullptr);

    attn<<<NIMG * WINS, 256, 0, stream>>>(qb, kb, vb, rpb, ob);

    pw_gemm<3><<<gg, 256, 0, stream>>>(ob, Wb + 3 * WMAT, pj_b, 1.0f, nullptr, (float*)d_out);
}

// Round 8
// 412.366 us; speedup vs baseline: 1.0585x; 1.0025x over previous
//
#include <hip/hip_runtime.h>

#define CCH 384
#define HH 192
#define WWD 192
#define NIMG 2
#define HWP (HH * WWD)        // 36864 pixels per image
#define PTOT (NIMG * HWP)     // 73728
#define HEADS 12
#define HD 32
#define NWIN 24
#define WINS 576              // windows per image
#define EELEM ((size_t)NIMG * CCH * HWP)   // elems per tensor (28,311,552)
#define WMAT 147456           // 384*384

typedef __attribute__((ext_vector_type(8))) short bh8;            // 8 bf16 (MFMA frag)
typedef __attribute__((ext_vector_type(8))) unsigned short us8;
typedef __attribute__((ext_vector_type(4))) unsigned short us4;
typedef __attribute__((ext_vector_type(4))) float fx4;

__device__ __forceinline__ unsigned short f2bf(float f) {
    unsigned u = __float_as_uint(f);
    u += 0x7fffu + ((u >> 16) & 1u);      // round-to-nearest-even
    return (unsigned short)(u >> 16);
}

__device__ __forceinline__ void gload16(const void* g, void* l) {
    __builtin_amdgcn_global_load_lds(
        (const __attribute__((address_space(1))) void*)g,
        (__attribute__((address_space(3))) void*)l, 16, 0, 0);
}

// ---------------------------------------------------------------------------
// weights fp32 -> bf16 (qp_w, kp_w, vp_w, proj_w concatenated)
// ---------------------------------------------------------------------------
__global__ __launch_bounds__(256) void wcvt(
    const float* __restrict__ a, const float* __restrict__ b,
    const float* __restrict__ c, const float* __restrict__ d,
    unsigned short* __restrict__ o)
{
    int idx8 = (blockIdx.x * 256 + threadIdx.x) * 8;
    int which = idx8 / WMAT;
    int loc = idx8 - which * WMAT;
    const float* s = (which == 0) ? a : (which == 1) ? b : (which == 2) ? c : d;
    float4 v0 = *(const float4*)(s + loc);
    float4 v1 = *(const float4*)(s + loc + 4);
    us8 ov;
    ov[0] = f2bf(v0.x); ov[1] = f2bf(v0.y); ov[2] = f2bf(v0.z); ov[3] = f2bf(v0.w);
    ov[4] = f2bf(v1.x); ov[5] = f2bf(v1.y); ov[6] = f2bf(v1.z); ov[7] = f2bf(v1.w);
    *(us8*)(o + idx8) = ov;
}

// ---------------------------------------------------------------------------
// depthwise weight transpose: [384][9] -> [9][384] fp32, for q,k,v.
// ---------------------------------------------------------------------------
__global__ __launch_bounds__(256) void wprep(
    const float* __restrict__ q, const float* __restrict__ k,
    const float* __restrict__ v, float* __restrict__ o)
{
    int idx = blockIdx.x * 256 + threadIdx.x;
    if (idx >= 3 * 9 * CCH) return;
    int ten = idx / (9 * CCH);
    int rem = idx - ten * (9 * CCH);
    int tap = rem / CCH;
    int c   = rem - tap * CCH;
    const float* s = (ten == 0) ? q : (ten == 1) ? k : v;
    o[idx] = s[c * 9 + tap];
}

// ---------------------------------------------------------------------------
// FUSED depthwise 3x3 + bias + window-gather transpose (v7: register sliding
// window -- 40 LDS reads/thread instead of 144).
// Block = ONE window (8x8) x 64 channels; grid = 6912 (8 x 864 XCD swizzle).
// LDS halo: [64 ch][10 rows][12 cols] f32, stride 121 (odd -> 2-way free).
// Thread = channel c x 2 pixel rows (16 px).
// ---------------------------------------------------------------------------
__global__ __launch_bounds__(256) void dwgather(
    const float* __restrict__ x,
    const float* __restrict__ wt,       // [3][9][384] fp32 transposed dw weights
    const float* __restrict__ qb, const float* __restrict__ kb,
    const float* __restrict__ vb,
    unsigned short* __restrict__ oq, unsigned short* __restrict__ ok,
    unsigned short* __restrict__ ov)
{
    __shared__ float halo[64 * 121];        // 30.25 KB

    // bijective XCD swizzle: 6912 = 8 * 864
    int bid = blockIdx.x;
    int b = (bid & 7) * 864 + (bid >> 3);
    int wtx  = b % 24;
    int strip = b / 24;                     // 0..287
    int chv  = strip % 6;
    int nwy  = strip / 6;                   // 0..47
    int wy   = nwy % 24;
    int n    = nwy / 24;

    int h0 = wy * 8, w0 = wtx * 8;
    int tid = threadIdx.x;
    int c   = tid & 63;                     // channel within chunk (lane-varying)
    int pxg = tid >> 6;                     // wave id: owns pixel rows 2pxg,2pxg+1
    int cg  = chv * 64 + c;
    int widx = n * WINS + wy * NWIN + wtx;

    const float* xbase = x + (size_t)n * CCH * HWP + (size_t)(chv * 64) * HWP;

    // ---- stage halo: 64ch x 10 rows x 12 cols (cols w0-2 .. w0+9) ----
    for (int j = tid; j < 1920; j += 256) {
        int seg = j % 3;
        int t   = j / 3;
        int rr  = t % 10;
        int cc  = t / 10;
        int hr  = h0 - 1 + rr;
        int cb  = w0 - 2 + seg * 4;
        float4 val = make_float4(0.f, 0.f, 0.f, 0.f);
        if (hr >= 0 && hr < HH) {
            const float* p = xbase + (size_t)cc * HWP + (size_t)hr * WWD;
            if (cb >= 0 && cb + 4 <= WWD) {
                val = *(const float4*)(p + cb);
            } else {
                if (cb + 0 >= 0 && cb + 0 < WWD) val.x = p[cb + 0];
                if (cb + 1 >= 0 && cb + 1 < WWD) val.y = p[cb + 1];
                if (cb + 2 >= 0 && cb + 2 < WWD) val.z = p[cb + 2];
                if (cb + 3 >= 0 && cb + 3 < WWD) val.w = p[cb + 3];
            }
        }
        int hb = cc * 121 + rr * 12 + seg * 4;
        halo[hb + 0] = val.x;
        halo[hb + 1] = val.y;
        halo[hb + 2] = val.z;
        halo[hb + 3] = val.w;
    }

    // ---- per-lane weights, coalesced ([tap][384] layout) ----
    float wq[9], wk[9], wv[9];
#pragma unroll
    for (int t = 0; t < 9; ++t) {
        wq[t] = wt[t * CCH + cg];
        wk[t] = wt[9 * CCH + t * CCH + cg];
        wv[t] = wt[18 * CCH + t * CCH + cg];
    }
    float bqv = qb[cg], bkv = kb[cg], bvv = vb[cg];

    __syncthreads();

    // ---- register sliding window: rows 2pxg..2pxg+3, cols 1..10 ----
    const int hbase = c * 121 + (2 * pxg) * 12;
    float r0[10], r1[10], r2[10];
#pragma unroll
    for (int cc = 0; cc < 10; ++cc) r0[cc] = halo[hbase + cc + 1];
#pragma unroll
    for (int cc = 0; cc < 10; ++cc) r1[cc] = halo[hbase + 12 + cc + 1];
#pragma unroll
    for (int cc = 0; cc < 10; ++cc) r2[cc] = halo[hbase + 24 + cc + 1];

    size_t ob0 = ((size_t)widx * 64 + pxg * 16) * CCH + cg;

    // pixel row 0 (px = pxg*16 + 0..7): taps rows r0,r1,r2
#pragma unroll
    for (int pc = 0; pc < 8; ++pc) {
        float sq = 0.f, sk = 0.f, sv = 0.f;
#pragma unroll
        for (int dc = 0; dc < 3; ++dc) {
            float x0 = r0[pc + dc], x1 = r1[pc + dc], x2 = r2[pc + dc];
            sq = fmaf(x0, wq[dc], sq);     sk = fmaf(x0, wk[dc], sk);     sv = fmaf(x0, wv[dc], sv);
            sq = fmaf(x1, wq[3 + dc], sq); sk = fmaf(x1, wk[3 + dc], sk); sv = fmaf(x1, wv[3 + dc], sv);
            sq = fmaf(x2, wq[6 + dc], sq); sk = fmaf(x2, wk[6 + dc], sk); sv = fmaf(x2, wv[6 + dc], sv);
        }
        size_t o = ob0 + (size_t)pc * CCH;
        oq[o] = f2bf(sq + bqv);
        ok[o] = f2bf(sk + bkv);
        ov[o] = f2bf(sv + bvv);
    }

    // rotate: r0 <- row 2pxg+3
#pragma unroll
    for (int cc = 0; cc < 10; ++cc) r0[cc] = halo[hbase + 36 + cc + 1];

    // pixel row 1 (px = pxg*16 + 8..15): taps rows r1,r2,r0
#pragma unroll
    for (int pc = 0; pc < 8; ++pc) {
        float sq = 0.f, sk = 0.f, sv = 0.f;
#pragma unroll
        for (int dc = 0; dc < 3; ++dc) {
            float x0 = r1[pc + dc], x1 = r2[pc + dc], x2 = r0[pc + dc];
            sq = fmaf(x0, wq[dc], sq);     sk = fmaf(x0, wk[dc], sk);     sv = fmaf(x0, wv[dc], sv);
            sq = fmaf(x1, wq[3 + dc], sq); sk = fmaf(x1, wk[3 + dc], sk); sv = fmaf(x1, wv[3 + dc], sv);
            sq = fmaf(x2, wq[6 + dc], sq); sk = fmaf(x2, wk[6 + dc], sk); sv = fmaf(x2, wv[6 + dc], sv);
        }
        size_t o = ob0 + (size_t)(8 + pc) * CCH;
        oq[o] = f2bf(sq + bqv);
        ok[o] = f2bf(sk + bkv);
        ov[o] = f2bf(sv + bvv);
    }
}

// ---------------------------------------------------------------------------
// bf16 MFMA GEMM (double-buffered global_load_lds, 1 barrier per K-step).
// Y: bf16 [p_wg][384]; W: bf16 [c_out][384]. 128x128 tile, BK=32, 4 waves.
// ORIENT 1: D[c][p] -> out bf16 [p][c], (acc+bias)*scale      (q, k)
// ORIENT 2: D[p][c] -> out bf16 [n][c][p_local], acc+bias     (v, transposed)
// ORIENT 3: D[p][c] -> out fp32 std [n][c][h][w], un-gather   (proj)
// ---------------------------------------------------------------------------
template<int ORIENT>
__global__ __launch_bounds__(256) void pw_gemm(
    const unsigned short* __restrict__ Y, const unsigned short* __restrict__ Wb,
    const float* __restrict__ bias, float scale,
    unsigned short* __restrict__ outb, float* __restrict__ outf)
{
    __shared__ unsigned short Wt[2][128][32];   // linear, gload_lds dest
    __shared__ unsigned short Yt[2][128][32];

    int tid = threadIdx.x;
    int pp0 = blockIdx.x * 128;
    int cm0 = blockIdx.y * 128;
    int lid = tid & 63, wid = tid >> 6;
    int wr = wid >> 1, wc = wid & 1;
    int li = lid & 15, g = lid >> 4;

    // staging geometry: wave stages rows wid*32..+31; one issue = 16 rows
    int srow = (lid >> 2);               // 0..15 within 16-row group
    int scol = (lid & 3) * 8;            // 0,8,16,24 (u16)

    fx4 acc[4][4];
#pragma unroll
    for (int i = 0; i < 4; ++i)
#pragma unroll
        for (int j = 0; j < 4; ++j) acc[i][j] = (fx4){0.f, 0.f, 0.f, 0.f};

    typedef unsigned short (*tile3)[128][32];
    tile3 A3 = (ORIENT == 1) ? Wt : Yt;
    tile3 B3 = (ORIENT == 1) ? Yt : Wt;

    const unsigned short* Wg0 = Wb + (size_t)(cm0 + wid * 32 + srow) * CCH + scol;
    const unsigned short* Yg0 = Y  + (size_t)(pp0 + wid * 32 + srow) * CCH + scol;

    // prologue: stage tile 0 into buffer 0
#pragma unroll
    for (int qi = 0; qi < 2; ++qi) {
        gload16(Wg0 + (size_t)qi * 16 * CCH, &Wt[0][wid * 32 + qi * 16][0]);
        gload16(Yg0 + (size_t)qi * 16 * CCH, &Yt[0][wid * 32 + qi * 16][0]);
    }
    __syncthreads();                     // vmcnt(0) drain + barrier

    for (int kt = 0; kt < 12; ++kt) {
        int cur = kt & 1;
        if (kt < 11) {                   // issue NEXT tile (overlaps MFMA below)
            int k1 = (kt + 1) * 32;
#pragma unroll
            for (int qi = 0; qi < 2; ++qi) {
                gload16(Wg0 + (size_t)qi * 16 * CCH + k1, &Wt[cur ^ 1][wid * 32 + qi * 16][0]);
                gload16(Yg0 + (size_t)qi * 16 * CCH + k1, &Yt[cur ^ 1][wid * 32 + qi * 16][0]);
            }
        }

        bh8 a[4], b[4];
#pragma unroll
        for (int mf = 0; mf < 4; ++mf)
            a[mf] = *(const bh8*)&A3[cur][wr * 64 + mf * 16 + li][g * 8];
#pragma unroll
        for (int nf = 0; nf < 4; ++nf)
            b[nf] = *(const bh8*)&B3[cur][wc * 64 + nf * 16 + li][g * 8];
#pragma unroll
        for (int mf = 0; mf < 4; ++mf)
#pragma unroll
            for (int nf = 0; nf < 4; ++nf)
                acc[mf][nf] = __builtin_amdgcn_mfma_f32_16x16x32_bf16(
                    a[mf], b[nf], acc[mf][nf], 0, 0, 0);

        __syncthreads();                 // drains vmcnt(0): next tile ready
    }

    if (ORIENT == 1) {
#pragma unroll
        for (int mf = 0; mf < 4; ++mf) {
            int c = cm0 + wr * 64 + mf * 16 + g * 4;
            float4 bv = *(const float4*)&bias[c];
#pragma unroll
            for (int nf = 0; nf < 4; ++nf) {
                int p = pp0 + wc * 64 + nf * 16 + li;
                us4 o;
                o[0] = f2bf((acc[mf][nf][0] + bv.x) * scale);
                o[1] = f2bf((acc[mf][nf][1] + bv.y) * scale);
                o[2] = f2bf((acc[mf][nf][2] + bv.z) * scale);
                o[3] = f2bf((acc[mf][nf][3] + bv.w) * scale);
                *(us4*)(outb + (size_t)p * CCH + c) = o;
            }
        }
    } else if (ORIENT == 2) {
#pragma unroll
        for (int nf = 0; nf < 4; ++nf) {
            int c = cm0 + wc * 64 + nf * 16 + li;
            float bv = bias[c];
#pragma unroll
            for (int mf = 0; mf < 4; ++mf) {
                int p = pp0 + wr * 64 + mf * 16 + g * 4;
                int n = p / HWP;
                int pl = p - n * HWP;
                us4 o;
                o[0] = f2bf(acc[mf][nf][0] + bv);
                o[1] = f2bf(acc[mf][nf][1] + bv);
                o[2] = f2bf(acc[mf][nf][2] + bv);
                o[3] = f2bf(acc[mf][nf][3] + bv);
                *(us4*)(outb + (size_t)(n * CCH + c) * HWP + pl) = o;
            }
        }
    } else {   // ORIENT 3: fp32 std layout, inverse window gather
#pragma unroll
        for (int nf = 0; nf < 4; ++nf) {
            int c = cm0 + wc * 64 + nf * 16 + li;
            float bv = bias[c];
#pragma unroll
            for (int mf = 0; mf < 4; ++mf) {
                int p = pp0 + wr * 64 + mf * 16 + g * 4;
                int n = p / HWP;
                int rem = p - n * HWP;
                int win = rem >> 6, t = rem & 63;
                int h = (win / NWIN) * 8 + (t >> 3);
                int w = (win % NWIN) * 8 + (t & 7);
                float4 o;
                o.x = acc[mf][nf][0] + bv;
                o.y = acc[mf][nf][1] + bv;
                o.z = acc[mf][nf][2] + bv;
                o.w = acc[mf][nf][3] + bv;
                *(float4*)(outf + (size_t)(n * CCH + c) * HWP + h * WWD + w) = o;
            }
        }
    }
}

// ---------------------------------------------------------------------------
// MFMA window attention. block = one window (64 tokens); 4 waves x 3 heads.
// q,k: bf16 [p_wg][384]; v: bf16 [n][c][p_local] (= V^T); out: bf16 [p_wg][384].
// ---------------------------------------------------------------------------
__global__ __launch_bounds__(256) void attn(
    const unsigned short* __restrict__ q, const unsigned short* __restrict__ k,
    const unsigned short* __restrict__ v, const float* __restrict__ rpb,
    unsigned short* __restrict__ o)
{
    __shared__ float rpbs[225 * HEADS];
    __shared__ unsigned short Pl[4][64][72];

    int tid = threadIdx.x, lid = tid & 63, wid = tid >> 6;
    int wl = blockIdx.x;
    int n = wl / WINS, winl = wl - n * WINS;
    int li = lid & 15, g = lid >> 4;

    for (int i = tid; i < 225 * HEADS; i += 256) rpbs[i] = rpb[i];
    __syncthreads();

    const fx4 z = (fx4){0.f, 0.f, 0.f, 0.f};

    for (int hq = wid; hq < HEADS; hq += 4) {
        const unsigned short* qp = q + (size_t)(wl * 64) * CCH + hq * HD + g * 8;
        const unsigned short* kp = k + (size_t)(wl * 64) * CCH + hq * HD + g * 8;
        bh8 aq[4], bk[4];
#pragma unroll
        for (int mf = 0; mf < 4; ++mf)
            aq[mf] = *(const bh8*)(qp + (size_t)(mf * 16 + li) * CCH);
#pragma unroll
        for (int nf = 0; nf < 4; ++nf)
            bk[nf] = *(const bh8*)(kp + (size_t)(nf * 16 + li) * CCH);

        fx4 s[4][4];
#pragma unroll
        for (int mf = 0; mf < 4; ++mf)
#pragma unroll
            for (int nf = 0; nf < 4; ++nf)
                s[mf][nf] = __builtin_amdgcn_mfma_f32_16x16x32_bf16(aq[mf], bk[nf], z, 0, 0, 0);

        // relative position bias (analytic index)
#pragma unroll
        for (int mf = 0; mf < 4; ++mf)
#pragma unroll
            for (int nf = 0; nf < 4; ++nf)
#pragma unroll
                for (int r = 0; r < 4; ++r) {
                    int tq = mf * 16 + g * 4 + r, tk = nf * 16 + li;
                    int dy = (tq >> 3) - (tk >> 3) + 7;
                    int dx = (tq & 7) - (tk & 7) + 7;
                    s[mf][nf][r] += rpbs[(dy * 15 + dx) * HEADS + hq];
                }

        // softmax across tk (lane group of 16 shares a row set)
        float inv_[4][4];
#pragma unroll
        for (int mf = 0; mf < 4; ++mf)
#pragma unroll
            for (int r = 0; r < 4; ++r) {
                float m = s[mf][0][r];
#pragma unroll
                for (int nf = 1; nf < 4; ++nf) m = fmaxf(m, s[mf][nf][r]);
                m = fmaxf(m, __shfl_xor(m, 1));
                m = fmaxf(m, __shfl_xor(m, 2));
                m = fmaxf(m, __shfl_xor(m, 4));
                m = fmaxf(m, __shfl_xor(m, 8));
                float sum = 0.f;
#pragma unroll
                for (int nf = 0; nf < 4; ++nf) {
                    float e = __expf(s[mf][nf][r] - m);
                    s[mf][nf][r] = e;
                    sum += e;
                }
                sum += __shfl_xor(sum, 1);
                sum += __shfl_xor(sum, 2);
                sum += __shfl_xor(sum, 4);
                sum += __shfl_xor(sum, 8);
                inv_[mf][r] = 1.f / sum;
            }

        // P -> per-wave LDS, bf16, row-major [tq][tk]
#pragma unroll
        for (int mf = 0; mf < 4; ++mf)
#pragma unroll
            for (int nf = 0; nf < 4; ++nf)
#pragma unroll
                for (int r = 0; r < 4; ++r)
                    Pl[wid][mf * 16 + g * 4 + r][nf * 16 + li] =
                        f2bf(s[mf][nf][r] * inv_[mf][r]);

        // O^T = V^T x P^T : D[d][tq]
        fx4 o2[2][4];
#pragma unroll
        for (int m2 = 0; m2 < 2; ++m2)
#pragma unroll
            for (int nf = 0; nf < 4; ++nf) o2[m2][nf] = z;
#pragma unroll
        for (int ks = 0; ks < 2; ++ks) {
            bh8 av[2], bp[4];
#pragma unroll
            for (int m2 = 0; m2 < 2; ++m2)
                av[m2] = *(const bh8*)(v + (size_t)(n * CCH + hq * HD + m2 * 16 + li) * HWP
                                         + winl * 64 + ks * 32 + g * 8);
#pragma unroll
            for (int nf = 0; nf < 4; ++nf)
                bp[nf] = *(const bh8*)&Pl[wid][nf * 16 + li][ks * 32 + g * 8];
#pragma unroll
            for (int m2 = 0; m2 < 2; ++m2)
#pragma unroll
                for (int nf = 0; nf < 4; ++nf)
                    o2[m2][nf] = __builtin_amdgcn_mfma_f32_16x16x32_bf16(
                        av[m2], bp[nf], o2[m2][nf], 0, 0, 0);
        }
#pragma unroll
        for (int nf = 0; nf < 4; ++nf) {
            int tq = nf * 16 + li;
#pragma unroll
            for (int m2 = 0; m2 < 2; ++m2) {
                int d = hq * HD + m2 * 16 + g * 4;
                us4 ov;
                ov[0] = f2bf(o2[m2][nf][0]);
                ov[1] = f2bf(o2[m2][nf][1]);
                ov[2] = f2bf(o2[m2][nf][2]);
                ov[3] = f2bf(o2[m2][nf][3]);
                *(us4*)(o + (size_t)(wl * 64 + tq) * CCH + d) = ov;
            }
        }
    }
}

// ---------------------------------------------------------------------------
extern "C" void kernel_launch(void* const* d_in, const int* in_sizes, int n_in,
                              void* d_out, int out_size, void* d_ws, size_t ws_size,
                              hipStream_t stream) {
    const float* vid  = (const float*)d_in[0];
    const float* qd_w = (const float*)d_in[1];
    const float* qd_b = (const float*)d_in[2];
    const float* qp_w = (const float*)d_in[3];
    const float* qp_b = (const float*)d_in[4];
    const float* kd_w = (const float*)d_in[5];
    const float* kd_b = (const float*)d_in[6];
    const float* kp_w = (const float*)d_in[7];
    const float* kp_b = (const float*)d_in[8];
    const float* vd_w = (const float*)d_in[9];
    const float* vd_b = (const float*)d_in[10];
    const float* vp_w = (const float*)d_in[11];
    const float* vp_b = (const float*)d_in[12];
    const float* rpb  = (const float*)d_in[13];
    const float* pj_w = (const float*)d_in[14];
    const float* pj_b = (const float*)d_in[15];

    unsigned short* ws16 = (unsigned short*)d_ws;
    unsigned short* tr0 = ws16 + 3 * EELEM;     // [p_wg][c] bf16 (q,k,v pre-GEMM)
    unsigned short* tr1 = ws16 + 4 * EELEM;
    unsigned short* tr2 = ws16 + 5 * EELEM;
    unsigned short* Wb  = ws16 + 6 * EELEM;     // 4 x 147456 bf16
    float* dwT          = (float*)(Wb + 4 * WMAT);  // [3][9][384] fp32
    unsigned short* qb  = ws16;                 // post-GEMM q,k,v
    unsigned short* kb  = ws16 + EELEM;
    unsigned short* vb  = ws16 + 2 * EELEM;
    unsigned short* ob  = tr0;                  // attn out reuses tr region

    wcvt<<<288, 256, 0, stream>>>(qp_w, kp_w, vp_w, pj_w, Wb);
    wprep<<<41, 256, 0, stream>>>(qd_w, kd_w, vd_w, dwT);
    dwgather<<<NIMG * WINS * 6, 256, 0, stream>>>(
        vid, dwT, qd_b, kd_b, vd_b, tr0, tr1, tr2);

    dim3 gg(PTOT / 128, 3);
    const float scale = 0.17677669529663687f;   // 32^-0.5 folded into q
    pw_gemm<1><<<gg, 256, 0, stream>>>(tr0, Wb,             qp_b, scale, qb, nullptr);
    pw_gemm<1><<<gg, 256, 0, stream>>>(tr1, Wb + WMAT,      kp_b, 1.0f,  kb, nullptr);
    pw_gemm<2><<<gg, 256, 0, stream>>>(tr2, Wb + 2 * WMAT,  vp_b, 1.0f,  vb, nullptr);

    attn<<<NIMG * WINS, 256, 0, stream>>>(qb, kb, vb, rpb, ob);

    pw_gemm<3><<<gg, 256, 0, stream>>>(ob, Wb + 3 * WMAT, pj_b, 1.0f, nullptr, (float*)d_out);
}